// Round 13
// baseline (423.657 us; speedup 1.0000x reference)
//
#include <hip/hip_runtime.h>
#include <hip/hip_bf16.h>
#include <stdint.h>

#define VOC 50257
#define HH  1024
#define II  512
#define HI  1536
#define TT  1024
#define G3  3072

typedef __attribute__((ext_vector_type(8))) short short8;
typedef __attribute__((ext_vector_type(4))) float f32x4;

typedef __attribute__((address_space(1))) const void gas_void;
typedef __attribute__((address_space(3))) void las_void;

__device__ __forceinline__ unsigned short f2bf(float f) {
  __hip_bfloat16 h = __float2bfloat16(f);
  unsigned short u;
  __builtin_memcpy(&u, &h, 2);
  return u;
}

__device__ __forceinline__ int4 pack8v(float4 a, float4 b) {
  int4 p;
  p.x = (int)f2bf(a.x) | ((int)f2bf(a.y) << 16);
  p.y = (int)f2bf(a.z) | ((int)f2bf(a.w) << 16);
  p.z = (int)f2bf(b.x) | ((int)f2bf(b.y) << 16);
  p.w = (int)f2bf(b.z) | ((int)f2bf(b.w) << 16);
  return p;
}

// ---------------------------------------------------------------------------
// K1: prologue (unchanged).
// ---------------------------------------------------------------------------
__global__ __launch_bounds__(256) void k_prologue(
    const float* __restrict__ z, const float* __restrict__ embed_w,
    const float* __restrict__ z2h_w, const float* __restrict__ z2h_b,
    const float* __restrict__ wih, const float* __restrict__ bih,
    const float* __restrict__ bhh,
    __hip_bfloat16* __restrict__ A, float* __restrict__ gxs,
    float* __restrict__ gxu, unsigned long long* __restrict__ h2) {
  __shared__ float sred[8];
  const int b = blockIdx.x;
  const int tid = threadIdx.x;
  if (b < G3) {
    const float* wrow = wih + (size_t)b * HI;
    float accs = 0.f, accu = 0.f;
    for (int c = tid; c < HI; c += 256) {
      float w = wrow[c];
      float xs, xu;
      if (c < HH) {
        float es = embed_w[HH + c];
        float eu = embed_w[2 * HH + c];
        xs = fmaxf(es, 0.f);
        xu = fmaxf(eu, 0.f);
      } else {
        xs = xu = z[c - HH];
      }
      accs = fmaf(w, xs, accs);
      accu = fmaf(w, xu, accu);
    }
    for (int o = 32; o > 0; o >>= 1) {
      accs += __shfl_down(accs, o);
      accu += __shfl_down(accu, o);
    }
    if ((tid & 63) == 0) { sred[tid >> 6] = accs; sred[4 + (tid >> 6)] = accu; }
    __syncthreads();
    if (tid == 0) {
      float rs = sred[0] + sred[1] + sred[2] + sred[3];
      float ru = sred[4] + sred[5] + sred[6] + sred[7];
      float base = bih[b] + ((b < 2 * HH) ? bhh[b] : 0.f);
      gxs[b] = rs + base;
      gxu[b] = ru + base;
    }
  } else if (b < G3 + HH) {
    const int j = b - G3;
    const float* wrow = z2h_w + (size_t)j * II;
    float acc = 0.f;
    for (int c = tid; c < II; c += 256) acc = fmaf(wrow[c], z[c], acc);
    for (int o = 32; o > 0; o >>= 1) acc += __shfl_down(acc, o);
    if ((tid & 63) == 0) sred[tid >> 6] = acc;
    __syncthreads();
    if (tid == 0) {
      float h0 = sred[0] + sred[1] + sred[2] + sred[3] + z2h_b[j];
      __hip_atomic_store(&h2[j], (unsigned long long)__float_as_uint(h0),
                         __ATOMIC_RELAXED, __HIP_MEMORY_SCOPE_AGENT);
      __hip_atomic_store(&h2[HH + j], 0xFFFFFFFF00000000ULL,
                         __ATOMIC_RELAXED, __HIP_MEMORY_SCOPE_AGENT);
    }
  } else {
    const int t = b - (G3 + HH);
    for (int i = tid; i < II; i += 256)
      A[(size_t)t * HI + HH + i] = __float2bfloat16(z[i]);
  }
}

// ---------------------------------------------------------------------------
// K2: register-direct persistent GRU scan. 32 blocks x 512 threads; NO cvt
// role (W reused once now -> bf16 pre-cvt strictly loses; removal also ends
// the 464MB stream that inflated every poll RTT). Per step, each lane polls
// its 16 h values (h[l+64k]) straight from global into registers — 16
// coalesced 512B loads — no LDS, no barrier. h_old for the wave's 4 owned
// elements stays in registers (last step's own hn). Convergence is a BIT in
// the published tag (set when the wave's 4 elems moved <= 2e-5); each wave
// observes all 1024 bits while polling -> __all() -> identical exit
// decision everywhere, zero extra communication, checked every step.
// Slot safety (2-slot wrap, per-wave): X publishes t+1 only after observing
// ALL of tag t; tag t of Y's elems requires Y to have finished step t-1
// (incl. reading tag t-1) -> no overwrite-while-reading. Same as before.
// ---------------------------------------------------------------------------
__global__ __launch_bounds__(512, 1) void k_gru(
    const float* __restrict__ whh, const float* __restrict__ bhh,
    const float* __restrict__ gxs, const float* __restrict__ gxu,
    unsigned long long* __restrict__ h2, __hip_bfloat16* __restrict__ A,
    int* __restrict__ meta) {
  const int tid = threadIdx.x;
  const int w = tid >> 6;
  const int l = tid & 63;
  const int wg = blockIdx.x;
  const int ebase = (wg << 5) + (w << 2);

  __shared__ float gxl[8][2][12];
  __shared__ float bhnl[8][4];

  if (l < 12) {
    const int q = l >> 2, i = l & 3;
    const int grow = q * HH + ebase + i;
    gxl[w][0][l] = gxs[grow];
    gxl[w][1][l] = gxu[grow];
    if (l < 4) bhnl[w][l] = bhh[2 * HH + ebase + l];
  }
  // no __syncthreads needed: gxl[w]/bhnl[w] are written and read only by
  // wave w (wave-lockstep + compiler lgkmcnt ordering suffice).

  float wreg[12][16];
#pragma unroll
  for (int jj = 0; jj < 12; ++jj) {
    const int grow = (jj >> 2) * HH + ebase + (jj & 3);
    const float* wrow = whh + (size_t)grow * HH;
#pragma unroll
    for (int k = 0; k < 16; ++k) wreg[jj][k] = wrow[l + (k << 6)];
  }

  // h_old for the 4 owned elements (slot0 tag0 = h0, written by prologue)
  float hp0 = __uint_as_float((unsigned)__hip_atomic_load(
      h2 + ebase + 0, __ATOMIC_RELAXED, __HIP_MEMORY_SCOPE_AGENT));
  float hp1 = __uint_as_float((unsigned)__hip_atomic_load(
      h2 + ebase + 1, __ATOMIC_RELAXED, __HIP_MEMORY_SCOPE_AGENT));
  float hp2 = __uint_as_float((unsigned)__hip_atomic_load(
      h2 + ebase + 2, __ATOMIC_RELAXED, __HIP_MEMORY_SCOPE_AGENT));
  float hp3 = __uint_as_float((unsigned)__hip_atomic_load(
      h2 + ebase + 3, __ATOMIC_RELAXED, __HIP_MEMORY_SCOPE_AGENT));

  float hv[16];
  bool convf = false;
  int t = 0;
  for (; t < TT; ++t) {
    const unsigned long long* hpp = h2 + ((t & 1) << 10);
    bool cb = true;
#pragma unroll
    for (int b = 0; b < 2; ++b) {
      unsigned long long vv[8];
      unsigned m = 0;
      do {
#pragma unroll
        for (int k = 0; k < 8; ++k)
          if (!(m & (1u << k)))
            vv[k] = __hip_atomic_load(hpp + l + (((b << 3) + k) << 6),
                                      __ATOMIC_RELAXED, __HIP_MEMORY_SCOPE_AGENT);
#pragma unroll
        for (int k = 0; k < 8; ++k)
          if (((unsigned)(vv[k] >> 32) & 0x7fffffffu) == (unsigned)t)
            m |= (1u << k);
      } while (m != 0xffu);
#pragma unroll
      for (int k = 0; k < 8; ++k) {
        hv[(b << 3) + k] = __uint_as_float((unsigned)vv[k]);
        cb = cb & ((vv[k] >> 63) != 0);
      }
    }
    if (__all(cb ? 1 : 0)) { convf = true; break; }

    const float* gx = &gxl[w][t ? 1 : 0][0];
    float hn0, hn1, hn2, hn3;
#pragma unroll
    for (int i = 0; i < 4; ++i) {
      float s0 = 0.f, s1 = 0.f, s2 = 0.f;
#pragma unroll
      for (int k = 0; k < 16; ++k) {
        s0 = fmaf(wreg[i][k], hv[k], s0);
        s1 = fmaf(wreg[4 + i][k], hv[k], s1);
        s2 = fmaf(wreg[8 + i][k], hv[k], s2);
      }
#pragma unroll
      for (int o = 1; o < 64; o <<= 1) {
        s0 += __shfl_xor(s0, o);
        s1 += __shfl_xor(s1, o);
        s2 += __shfl_xor(s2, o);
      }
      const float hpv = (i == 0) ? hp0 : (i == 1) ? hp1 : (i == 2) ? hp2 : hp3;
      const float r = 1.f / (1.f + __expf(-(gx[i] + s0)));
      const float u = 1.f / (1.f + __expf(-(gx[4 + i] + s1)));
      const float nin = gx[8 + i] + r * (s2 + bhnl[w][i]);
      const float ex = __expf(2.f * nin);
      const float n = 1.f - 2.f / (ex + 1.f);
      const float hnew = (1.f - u) * n + u * hpv;
      if (i == 0) hn0 = hnew;
      else if (i == 1) hn1 = hnew;
      else if (i == 2) hn2 = hnew;
      else hn3 = hnew;
    }
    const bool myconv =
        fabsf(hn0 - hp0) <= 2e-5f && fabsf(hn1 - hp1) <= 2e-5f &&
        fabsf(hn2 - hp2) <= 2e-5f && fabsf(hn3 - hp3) <= 2e-5f;
    if (l < 4) {
      const float hsel = (l == 0) ? hn0 : (l == 1) ? hn1 : (l == 2) ? hn2 : hn3;
      const unsigned tag = (unsigned)(t + 1) | (myconv ? 0x80000000u : 0u);
      const unsigned long long pk =
          ((unsigned long long)tag << 32) |
          (unsigned long long)__float_as_uint(hsel);
      __hip_atomic_store(h2 + (((t + 1) & 1) << 10) + ebase + l, pk,
                         __ATOMIC_RELAXED, __HIP_MEMORY_SCOPE_AGENT);
      A[(size_t)t * HI + ebase + l] = __float2bfloat16(hsel);
    }
    hp0 = hn0; hp1 = hn1; hp2 = hn2; hp3 = hn3;
  }

  // epilogue: A rows [t, mpad) <- h_t. Col c=wg*32+j is held by lane
  // ((wg&1)*32+j) at hv[wg>>1] (runtime-uniform -> unrolled select).
  if (convf) {
    const int mpad = ((t + 127) >> 7) << 7;
    if (t < mpad) {
      const int kk = wg >> 1;
      float sel = 0.f;
#pragma unroll
      for (int k = 0; k < 16; ++k)
        if (k == kk) sel = hv[k];
      const int jl = l - ((wg & 1) << 5);
      if (jl >= 0 && jl < 32) {
        const __hip_bfloat16 hb = __float2bfloat16(sel);
        const int c = (wg << 5) + jl;
        for (int r = t + w; r < mpad; r += 8)
          A[(size_t)r * HI + c] = hb;
      }
    }
  }
  if (wg == 0 && tid == 0) {
    meta[0] = t;
    meta[1] = (t >= TT) ? TT : (((t + 127) >> 7) << 7);
  }
}

// ---------------------------------------------------------------------------
// K3: logits GEMM (round-5-proven fp32-W structure, verbatim) with
// mtile=bid/393 mapping (active blocks spread across XCDs under early-exit)
// and meta-based exit for m0 >= mpad. No W pre-cvt: with one active m-tile
// W is read exactly once either way, and fp32-direct avoids the cvt's
// 464MB stream during the scan.
// ---------------------------------------------------------------------------
__global__ __launch_bounds__(256, 2) void k_gemm9(
    const short* __restrict__ A, const float* __restrict__ out_w,
    const float* __restrict__ out_b, float* __restrict__ out,
    const int* __restrict__ meta) {
  __shared__ __align__(16) short As[2][4096];
  __shared__ __align__(16) short Ws[2][4096];

  const int tid = threadIdx.x;
  const int w = tid >> 6, l = tid & 63;
  const int wm = w >> 1, wn = w & 1;

  const int mtile = blockIdx.x / 393;
  const int band = blockIdx.x - mtile * 393;
  const int m0 = mtile << 7;
  const int n0 = band << 7;

  if (m0 >= meta[1]) return;

  f32x4 acc[4][4];
#pragma unroll
  for (int i = 0; i < 4; ++i)
#pragma unroll
    for (int j = 0; j < 4; ++j) acc[i][j] = (f32x4){0.f, 0.f, 0.f, 0.f};

  const int arow0 = (w << 5) + (l >> 2);
  const int agp = l & 3;
  const char* Abytes = (const char*)A;
  const char* asrc0 = Abytes + (size_t)(m0 + arow0) * 3072 +
                      ((agp ^ ((arow0 >> 1) & 3)) << 4);
  const int arow1 = arow0 + 16;
  const char* asrc1 = Abytes + (size_t)(m0 + arow1) * 3072 +
                      ((agp ^ ((arow1 >> 1) & 3)) << 4);

  const int wrowi = tid >> 1;
  const int hh = tid & 1;
  const int sw = (wrowi >> 1) & 3;
  const int gbase = (hh << 1) ^ (sw & 2);
  const int sel = sw & 1;
  const int wrow_c = (n0 + wrowi < VOC) ? (n0 + wrowi) : (VOC - 1);
  const float* wsrc = out_w + (size_t)wrow_c * HI + (gbase << 3);

  float4 wq0, wq1, wq2, wq3;

#define STAGEA(b, t)                                                          \
  {                                                                           \
    __builtin_amdgcn_global_load_lds((gas_void*)(asrc0 + (t) * 64),           \
        (las_void*)&As[b][(w << 1) << 9], 16, 0, 0);                          \
    __builtin_amdgcn_global_load_lds((gas_void*)(asrc1 + (t) * 64),           \
        (las_void*)&As[b][((w << 1) + 1) << 9], 16, 0, 0);                    \
  }
#define LOADW(t)                                                              \
  {                                                                           \
    const float* s_ = wsrc + (t) * 32;                                        \
    wq0 = *(const float4*)(s_);                                               \
    wq1 = *(const float4*)(s_ + 4);                                           \
    wq2 = *(const float4*)(s_ + 8);                                           \
    wq3 = *(const float4*)(s_ + 12);                                          \
  }
#define PACKW(b)                                                              \
  {                                                                           \
    int4 lo = pack8v(wq0, wq1), hi = pack8v(wq2, wq3);                        \
    int4 ga_ = sel ? hi : lo, gb_ = sel ? lo : hi;                            \
    *(int4*)&Ws[b][tid << 4] = ga_;                                           \
    *(int4*)&Ws[b][(tid << 4) + 8] = gb_;                                     \
  }
#define CONSUME(b)                                                            \
  {                                                                           \
    const int q_ = l >> 4, rl_ = l & 15;                                      \
    short8 bfr[4];                                                            \
    _Pragma("unroll") for (int nt = 0; nt < 4; ++nt) {                        \
      const int rn = (wn << 6) + (nt << 4) + rl_;                             \
      bfr[nt] = *(const short8*)&Ws[b][(rn << 5) +                            \
                                       ((q_ ^ ((rn >> 1) & 3)) << 3)];        \
    }                                                                         \
    _Pragma("unroll") for (int mt = 0; mt < 4; ++mt) {                        \
      const int rm = (wm << 6) + (mt << 4) + rl_;                             \
      short8 af = *(const short8*)&As[b][(rm << 5) +                          \
                                         ((q_ ^ ((rm >> 1) & 3)) << 3)];      \
      _Pragma("unroll") for (int nt = 0; nt < 4; ++nt)                        \
          acc[nt][mt] = __builtin_amdgcn_mfma_f32_16x16x32_bf16(              \
              af, bfr[nt], acc[nt][mt], 0, 0, 0);                             \
    }                                                                         \
  }

  STAGEA(0, 0);
  LOADW(0);
  PACKW(0);
  __syncthreads();

  for (int t = 0; t < 48; ++t) {
    const int b = t & 1;
    if (t < 47) {
      STAGEA(b ^ 1, t + 1);
      LOADW(t + 1);
    }
    CONSUME(b);
    if (t < 47) PACKW(b ^ 1);
    __syncthreads();
  }

#pragma unroll
  for (int nt = 0; nt < 4; ++nt) {
    const int col = n0 + (wn << 6) + (nt << 4) + (l & 15);
    if (col < VOC) {
      const float bias = out_b[col];
      const int rbase = m0 + (wm << 6) + ((l >> 4) << 2);
#pragma unroll
      for (int mt = 0; mt < 4; ++mt)
#pragma unroll
        for (int q = 0; q < 4; ++q)
          out[(size_t)(rbase + (mt << 4) + q) * VOC + col] =
              acc[nt][mt][q] + bias;
    }
  }
#undef STAGEA
#undef LOADW
#undef PACKW
#undef CONSUME
}

// ---------------------------------------------------------------------------
// K4: row-fill (unchanged): copy logits row tc-1 to rows [mpad, 1024),
// one block per row, fully contiguous. No-op if mpad == 1024.
// ---------------------------------------------------------------------------
__global__ __launch_bounds__(256) void k_fill(
    const int* __restrict__ meta, float* __restrict__ out) {
  const int tc = meta[0], mpad = meta[1];
  const int r = mpad + blockIdx.x;
  if (r >= TT) return;
  const float* src = out + (size_t)(tc - 1) * VOC;
  float* dst = out + (size_t)r * VOC;
  const int tid = threadIdx.x;
  for (int i = tid; i < (VOC >> 2); i += 256) {
    f32x4 v;
    __builtin_memcpy(&v, src + ((size_t)i << 2), 16);
    __builtin_memcpy(dst + ((size_t)i << 2), &v, 16);
  }
  if (tid == 0) dst[VOC - 1] = src[VOC - 1];
}

extern "C" void kernel_launch(void* const* d_in, const int* in_sizes, int n_in,
                              void* d_out, int out_size, void* d_ws, size_t ws_size,
                              hipStream_t stream) {
  const float* z       = (const float*)d_in[0];
  const float* embed_w = (const float*)d_in[2];
  const float* z2h_w   = (const float*)d_in[3];
  const float* z2h_b   = (const float*)d_in[4];
  const float* wih     = (const float*)d_in[5];
  const float* whh     = (const float*)d_in[6];
  const float* bih     = (const float*)d_in[7];
  const float* bhh     = (const float*)d_in[8];
  const float* out_w   = (const float*)d_in[9];
  const float* out_b   = (const float*)d_in[10];
  float* out = (float*)d_out;

  char* ws = (char*)d_ws;
  __hip_bfloat16* A = (__hip_bfloat16*)ws;                      // 3,145,728 B
  float* gxs = (float*)(ws + 3145728);                          // 12,288 B
  float* gxu = (float*)(ws + 3145728 + 12288);                  // 12,288 B
  unsigned long long* h2 = (unsigned long long*)(ws + 3145728 + 24576);  // 16,384 B
  int* meta = (int*)(ws + 3145728 + 24576 + 16384);             // 8 B

  hipLaunchKernelGGL(k_prologue, dim3(5120), dim3(256), 0, stream,
                     z, embed_w, z2h_w, z2h_b, wih, bih, bhh, A, gxs, gxu, h2);
  hipLaunchKernelGGL(k_gru, dim3(32), dim3(512), 0, stream,
                     whh, bhh, gxs, gxu, h2, A, meta);
  hipLaunchKernelGGL(k_gemm9, dim3(3144), dim3(256), 0, stream,
                     (const short*)A, out_w, out_b, out, meta);
  hipLaunchKernelGGL(k_fill, dim3(896), dim3(256), 0, stream, meta, out);
}

// Round 14
// 379.846 us; speedup vs baseline: 1.1153x; 1.1153x over previous
//
#include <hip/hip_runtime.h>
#include <hip/hip_bf16.h>
#include <stdint.h>

#define VOC 50257
#define HH  1024
#define II  512
#define HI  1536
#define TT  1024
#define G3  3072

typedef __attribute__((ext_vector_type(8))) short short8;
typedef __attribute__((ext_vector_type(4))) float f32x4;

typedef __attribute__((address_space(1))) const void gas_void;
typedef __attribute__((address_space(3))) void las_void;

__device__ __forceinline__ unsigned short f2bf(float f) {
  __hip_bfloat16 h = __float2bfloat16(f);
  unsigned short u;
  __builtin_memcpy(&u, &h, 2);
  return u;
}

__device__ __forceinline__ int4 pack8v(float4 a, float4 b) {
  int4 p;
  p.x = (int)f2bf(a.x) | ((int)f2bf(a.y) << 16);
  p.y = (int)f2bf(a.z) | ((int)f2bf(a.w) << 16);
  p.z = (int)f2bf(b.x) | ((int)f2bf(b.y) << 16);
  p.w = (int)f2bf(b.z) | ((int)f2bf(b.w) << 16);
  return p;
}

// ---------------------------------------------------------------------------
// K1: prologue (unchanged).
// ---------------------------------------------------------------------------
__global__ __launch_bounds__(256) void k_prologue(
    const float* __restrict__ z, const float* __restrict__ embed_w,
    const float* __restrict__ z2h_w, const float* __restrict__ z2h_b,
    const float* __restrict__ wih, const float* __restrict__ bih,
    const float* __restrict__ bhh,
    __hip_bfloat16* __restrict__ A, float* __restrict__ gxs,
    float* __restrict__ gxu, unsigned long long* __restrict__ h2) {
  __shared__ float sred[8];
  const int b = blockIdx.x;
  const int tid = threadIdx.x;
  if (b < G3) {
    const float* wrow = wih + (size_t)b * HI;
    float accs = 0.f, accu = 0.f;
    for (int c = tid; c < HI; c += 256) {
      float w = wrow[c];
      float xs, xu;
      if (c < HH) {
        float es = embed_w[HH + c];
        float eu = embed_w[2 * HH + c];
        xs = fmaxf(es, 0.f);
        xu = fmaxf(eu, 0.f);
      } else {
        xs = xu = z[c - HH];
      }
      accs = fmaf(w, xs, accs);
      accu = fmaf(w, xu, accu);
    }
    for (int o = 32; o > 0; o >>= 1) {
      accs += __shfl_down(accs, o);
      accu += __shfl_down(accu, o);
    }
    if ((tid & 63) == 0) { sred[tid >> 6] = accs; sred[4 + (tid >> 6)] = accu; }
    __syncthreads();
    if (tid == 0) {
      float rs = sred[0] + sred[1] + sred[2] + sred[3];
      float ru = sred[4] + sred[5] + sred[6] + sred[7];
      float base = bih[b] + ((b < 2 * HH) ? bhh[b] : 0.f);
      gxs[b] = rs + base;
      gxu[b] = ru + base;
    }
  } else if (b < G3 + HH) {
    const int j = b - G3;
    const float* wrow = z2h_w + (size_t)j * II;
    float acc = 0.f;
    for (int c = tid; c < II; c += 256) acc = fmaf(wrow[c], z[c], acc);
    for (int o = 32; o > 0; o >>= 1) acc += __shfl_down(acc, o);
    if ((tid & 63) == 0) sred[tid >> 6] = acc;
    __syncthreads();
    if (tid == 0) {
      float h0 = sred[0] + sred[1] + sred[2] + sred[3] + z2h_b[j];
      __hip_atomic_store(&h2[j], (unsigned long long)__float_as_uint(h0),
                         __ATOMIC_RELAXED, __HIP_MEMORY_SCOPE_AGENT);
      __hip_atomic_store(&h2[HH + j], 0xFFFFFFFF00000000ULL,
                         __ATOMIC_RELAXED, __HIP_MEMORY_SCOPE_AGENT);
    }
  } else {
    const int t = b - (G3 + HH);
    for (int i = tid; i < II; i += 256)
      A[(size_t)t * HI + HH + i] = __float2bfloat16(z[i]);
  }
}

// ---------------------------------------------------------------------------
// K2: persistent GRU scan — REVERTED to the round-10 LDS-based structure
// (fastest measured: ~150us pure). Round-13's register-direct all-to-all
// regressed (+37us): every wave polled all 1024 elems itself in batched
// vmcnt(0) retries vs 2 loads/thread + LDS share here. 32 blocks, no cvt
// role. Convergence 2e-5 checked every 4 steps; exports {tc, mpad}.
// ---------------------------------------------------------------------------
__global__ __launch_bounds__(512, 1) void k_gru(
    const float* __restrict__ whh, const float* __restrict__ bhh,
    const float* __restrict__ gxs, const float* __restrict__ gxu,
    unsigned long long* __restrict__ h2, __hip_bfloat16* __restrict__ A,
    int* __restrict__ meta) {
  const int tid = threadIdx.x;
  const int w = tid >> 6;
  const int l = tid & 63;
  const int wg = blockIdx.x;
  const int ebase = (wg << 5) + (w << 2);

  __shared__ float h_lds[2][HH];
  __shared__ float gxl[8][2][12];
  __shared__ float bhnl[8][4];
  __shared__ int flags[2];

  if (l < 12) {
    const int q = l >> 2, i = l & 3;
    const int grow = q * HH + ebase + i;
    gxl[w][0][l] = gxs[grow];
    gxl[w][1][l] = gxu[grow];
    if (l < 4) bhnl[w][l] = bhh[2 * HH + ebase + l];
  }
  if (tid < 2) flags[tid] = 0;

  float wreg[12][16];
#pragma unroll
  for (int jj = 0; jj < 12; ++jj) {
    const int grow = (jj >> 2) * HH + ebase + (jj & 3);
    const float* wrow = whh + (size_t)grow * HH;
#pragma unroll
    for (int k = 0; k < 16; ++k) wreg[jj][k] = wrow[l + (k << 6)];
  }
  __syncthreads();

  const int i0 = tid, i1 = tid + 512;
  int t = 0;
  for (; t < TT; ++t) {
    const int p = t & 1;
    unsigned long long* hp = h2 + (p << 10);
    unsigned long long v0 = 0, v1 = 0;
    bool r0 = false, r1 = false;
    do {
      if (!r0) v0 = __hip_atomic_load(hp + i0, __ATOMIC_RELAXED, __HIP_MEMORY_SCOPE_AGENT);
      if (!r1) v1 = __hip_atomic_load(hp + i1, __ATOMIC_RELAXED, __HIP_MEMORY_SCOPE_AGENT);
      r0 = r0 | ((unsigned)(v0 >> 32) == (unsigned)t);
      r1 = r1 | ((unsigned)(v1 >> 32) == (unsigned)t);
    } while (!(r0 & r1));
    const float f0 = __uint_as_float((unsigned)v0);
    const float f1 = __uint_as_float((unsigned)v1);
    h_lds[p][i0] = f0;
    h_lds[p][i1] = f1;
    if ((t & 3) == 3) {
      const float d = fmaxf(fabsf(f0 - h_lds[p ^ 1][i0]), fabsf(f1 - h_lds[p ^ 1][i1]));
      if (d > 2e-5f) flags[(t >> 2) & 1] = 1;
    }
    __syncthreads();
    if ((t & 3) == 3) {
      const int sel = (t >> 2) & 1;
      const bool not_conv = flags[sel] != 0;
      if (tid == 0) flags[sel ^ 1] = 0;
      if (!not_conv) break;
    }

    float hv[16];
#pragma unroll
    for (int k = 0; k < 16; ++k) hv[k] = h_lds[p][l + (k << 6)];
    float s[12];
#pragma unroll
    for (int jj = 0; jj < 12; ++jj) {
      float a = 0.f;
#pragma unroll
      for (int k = 0; k < 16; ++k) a = fmaf(wreg[jj][k], hv[k], a);
#pragma unroll
      for (int o = 1; o < 64; o <<= 1) a += __shfl_xor(a, o);
      s[jj] = a;
    }

    const float* gx = &gxl[w][t ? 1 : 0][0];
    float hn0, hn1, hn2, hn3;
#pragma unroll
    for (int i = 0; i < 4; ++i) {
      const float r = 1.f / (1.f + __expf(-(gx[i] + s[i])));
      const float u = 1.f / (1.f + __expf(-(gx[4 + i] + s[4 + i])));
      const float nin = gx[8 + i] + r * (s[8 + i] + bhnl[w][i]);
      const float ex = __expf(2.f * nin);
      const float n = 1.f - 2.f / (ex + 1.f);
      const float hnew = (1.f - u) * n + u * h_lds[p][ebase + i];
      if (i == 0) hn0 = hnew;
      else if (i == 1) hn1 = hnew;
      else if (i == 2) hn2 = hnew;
      else hn3 = hnew;
    }
    if (l < 4) {
      const float hsel = (l == 0) ? hn0 : (l == 1) ? hn1 : (l == 2) ? hn2 : hn3;
      const int e = ebase + l;
      const unsigned long long pk =
          (((unsigned long long)(unsigned)(t + 1)) << 32) |
          (unsigned long long)__float_as_uint(hsel);
      __hip_atomic_store(h2 + (((t + 1) & 1) << 10) + e, pk,
                         __ATOMIC_RELAXED, __HIP_MEMORY_SCOPE_AGENT);
      A[(size_t)t * HI + e] = __float2bfloat16(hsel);
    }
  }

  const int tcv = t;
  const int mpad = (tcv >= TT) ? TT : (((tcv + 127) >> 7) << 7);
  if (tcv < mpad) {
    const int p = tcv & 1;
    const int total = (mpad - tcv) << 5;
    for (int idx = tid; idx < total; idx += 512) {
      const int rr = tcv + (idx >> 5);
      const int c = idx & 31;
      A[(size_t)rr * HI + (wg << 5) + c] =
          __float2bfloat16(h_lds[p][(wg << 5) + c]);
    }
  }
  if (wg == 0 && tid == 0) {
    meta[0] = tcv;
    meta[1] = mpad;
  }
}

// ---------------------------------------------------------------------------
// K3: logits GEMM (round-5-proven fp32-W structure) with mtile=bid/393 and
// meta early-exit. NEW: inactive blocks (m0 >= mpad) become W-PREFETCHERS —
// each streams a ~110KB chunk of out_w (loads kept live by an asm sink) so
// the 309MB W read is parallelized over all 256 CUs and the 393 active
// blocks' W loads hit L2/L3. Same total bytes, much better HBM saturation
// (round-13: 393 blocks alone sustained only ~2.9TB/s on the W stream).
// ---------------------------------------------------------------------------
__global__ __launch_bounds__(256, 2) void k_gemm9(
    const short* __restrict__ A, const float* __restrict__ out_w,
    const float* __restrict__ out_b, float* __restrict__ out,
    const int* __restrict__ meta) {
  __shared__ __align__(16) short As[2][4096];
  __shared__ __align__(16) short Ws[2][4096];

  const int tid = threadIdx.x;
  const int w = tid >> 6, l = tid & 63;
  const int wm = w >> 1, wn = w & 1;

  const int mtile = blockIdx.x / 393;
  const int band = blockIdx.x - mtile * 393;
  const int m0 = mtile << 7;
  const int n0 = band << 7;

  const int mpad = meta[1];
  if (m0 >= mpad) {
    // ---- W-prefetch role ----
    const int act = (mpad >> 7) * 393;
    const long long nin = 3144 - act;
    const long long total4 = (long long)VOC * HI / 4;  // 19,298,688 float4s
    const long long per = (total4 + nin - 1) / nin;
    const long long beg = (long long)(blockIdx.x - act) * per;
    long long end = beg + per;
    if (end > total4) end = total4;
    float s = 0.f;
    for (long long i = beg + tid; i < end; i += 256) {
      float4 v = *(const float4*)(out_w + (i << 2));
      s += v.x + v.y + v.z + v.w;
    }
    asm volatile("" :: "v"(s));  // keep loads live (cache-warm only)
    return;
  }

  f32x4 acc[4][4];
#pragma unroll
  for (int i = 0; i < 4; ++i)
#pragma unroll
    for (int j = 0; j < 4; ++j) acc[i][j] = (f32x4){0.f, 0.f, 0.f, 0.f};

  const int arow0 = (w << 5) + (l >> 2);
  const int agp = l & 3;
  const char* Abytes = (const char*)A;
  const char* asrc0 = Abytes + (size_t)(m0 + arow0) * 3072 +
                      ((agp ^ ((arow0 >> 1) & 3)) << 4);
  const int arow1 = arow0 + 16;
  const char* asrc1 = Abytes + (size_t)(m0 + arow1) * 3072 +
                      ((agp ^ ((arow1 >> 1) & 3)) << 4);

  const int wrowi = tid >> 1;
  const int hh = tid & 1;
  const int sw = (wrowi >> 1) & 3;
  const int gbase = (hh << 1) ^ (sw & 2);
  const int sel = sw & 1;
  const int wrow_c = (n0 + wrowi < VOC) ? (n0 + wrowi) : (VOC - 1);
  const float* wsrc = out_w + (size_t)wrow_c * HI + (gbase << 3);

  float4 wq0, wq1, wq2, wq3;

#define STAGEA(b, t)                                                          \
  {                                                                           \
    __builtin_amdgcn_global_load_lds((gas_void*)(asrc0 + (t) * 64),           \
        (las_void*)&As[b][(w << 1) << 9], 16, 0, 0);                          \
    __builtin_amdgcn_global_load_lds((gas_void*)(asrc1 + (t) * 64),           \
        (las_void*)&As[b][((w << 1) + 1) << 9], 16, 0, 0);                    \
  }
#define LOADW(t)                                                              \
  {                                                                           \
    const float* s_ = wsrc + (t) * 32;                                        \
    wq0 = *(const float4*)(s_);                                               \
    wq1 = *(const float4*)(s_ + 4);                                           \
    wq2 = *(const float4*)(s_ + 8);                                           \
    wq3 = *(const float4*)(s_ + 12);                                          \
  }
#define PACKW(b)                                                              \
  {                                                                           \
    int4 lo = pack8v(wq0, wq1), hi = pack8v(wq2, wq3);                        \
    int4 ga_ = sel ? hi : lo, gb_ = sel ? lo : hi;                            \
    *(int4*)&Ws[b][tid << 4] = ga_;                                           \
    *(int4*)&Ws[b][(tid << 4) + 8] = gb_;                                     \
  }
#define CONSUME(b)                                                            \
  {                                                                           \
    const int q_ = l >> 4, rl_ = l & 15;                                      \
    short8 bfr[4];                                                            \
    _Pragma("unroll") for (int nt = 0; nt < 4; ++nt) {                        \
      const int rn = (wn << 6) + (nt << 4) + rl_;                             \
      bfr[nt] = *(const short8*)&Ws[b][(rn << 5) +                            \
                                       ((q_ ^ ((rn >> 1) & 3)) << 3)];        \
    }                                                                         \
    _Pragma("unroll") for (int mt = 0; mt < 4; ++mt) {                        \
      const int rm = (wm << 6) + (mt << 4) + rl_;                             \
      short8 af = *(const short8*)&As[b][(rm << 5) +                          \
                                         ((q_ ^ ((rm >> 1) & 3)) << 3)];      \
      _Pragma("unroll") for (int nt = 0; nt < 4; ++nt)                        \
          acc[nt][mt] = __builtin_amdgcn_mfma_f32_16x16x32_bf16(              \
              af, bfr[nt], acc[nt][mt], 0, 0, 0);                             \
    }                                                                         \
  }

  STAGEA(0, 0);
  LOADW(0);
  PACKW(0);
  __syncthreads();

  for (int t = 0; t < 48; ++t) {
    const int b = t & 1;
    if (t < 47) {
      STAGEA(b ^ 1, t + 1);
      LOADW(t + 1);
    }
    CONSUME(b);
    if (t < 47) PACKW(b ^ 1);
    __syncthreads();
  }

#pragma unroll
  for (int nt = 0; nt < 4; ++nt) {
    const int col = n0 + (wn << 6) + (nt << 4) + (l & 15);
    if (col < VOC) {
      const float bias = out_b[col];
      const int rbase = m0 + (wm << 6) + ((l >> 4) << 2);
#pragma unroll
      for (int mt = 0; mt < 4; ++mt)
#pragma unroll
        for (int q = 0; q < 4; ++q)
          out[(size_t)(rbase + (mt << 4) + q) * VOC + col] =
              acc[nt][mt][q] + bias;
    }
  }
#undef STAGEA
#undef LOADW
#undef PACKW
#undef CONSUME
}

// ---------------------------------------------------------------------------
// K4: row-fill (unchanged): copy logits row tc-1 to rows [mpad, 1024),
// one block per row, fully contiguous. No-op if mpad == 1024.
// ---------------------------------------------------------------------------
__global__ __launch_bounds__(256) void k_fill(
    const int* __restrict__ meta, float* __restrict__ out) {
  const int tc = meta[0], mpad = meta[1];
  const int r = mpad + blockIdx.x;
  if (r >= TT) return;
  const float* src = out + (size_t)(tc - 1) * VOC;
  float* dst = out + (size_t)r * VOC;
  const int tid = threadIdx.x;
  for (int i = tid; i < (VOC >> 2); i += 256) {
    f32x4 v;
    __builtin_memcpy(&v, src + ((size_t)i << 2), 16);
    __builtin_memcpy(dst + ((size_t)i << 2), &v, 16);
  }
  if (tid == 0) dst[VOC - 1] = src[VOC - 1];
}

extern "C" void kernel_launch(void* const* d_in, const int* in_sizes, int n_in,
                              void* d_out, int out_size, void* d_ws, size_t ws_size,
                              hipStream_t stream) {
  const float* z       = (const float*)d_in[0];
  const float* embed_w = (const float*)d_in[2];
  const float* z2h_w   = (const float*)d_in[3];
  const float* z2h_b   = (const float*)d_in[4];
  const float* wih     = (const float*)d_in[5];
  const float* whh     = (const float*)d_in[6];
  const float* bih     = (const float*)d_in[7];
  const float* bhh     = (const float*)d_in[8];
  const float* out_w   = (const float*)d_in[9];
  const float* out_b   = (const float*)d_in[10];
  float* out = (float*)d_out;

  char* ws = (char*)d_ws;
  __hip_bfloat16* A = (__hip_bfloat16*)ws;                      // 3,145,728 B
  float* gxs = (float*)(ws + 3145728);                          // 12,288 B
  float* gxu = (float*)(ws + 3145728 + 12288);                  // 12,288 B
  unsigned long long* h2 = (unsigned long long*)(ws + 3145728 + 24576);  // 16,384 B
  int* meta = (int*)(ws + 3145728 + 24576 + 16384);             // 8 B

  hipLaunchKernelGGL(k_prologue, dim3(5120), dim3(256), 0, stream,
                     z, embed_w, z2h_w, z2h_b, wih, bih, bhh, A, gxs, gxu, h2);
  hipLaunchKernelGGL(k_gru, dim3(32), dim3(512), 0, stream,
                     whh, bhh, gxs, gxu, h2, A, meta);
  hipLaunchKernelGGL(k_gemm9, dim3(3144), dim3(256), 0, stream,
                     (const short*)A, out_w, out_b, out, meta);
  hipLaunchKernelGGL(k_fill, dim3(896), dim3(256), 0, stream, meta, out);
}